// Round 8
// baseline (112.120 us; speedup 1.0000x reference)
//
#include <hip/hip_runtime.h>

// CRF log-likelihood, MI355X. SEQ=512, B=1024, T=48.
// One wave (64-thread block) per batch chain, lane = tag.
// Linear-domain recurrence: r <- (r @ E) * exp(e)*2^-6, E=exp(trans) pinned in
// 48 VGPRs. Broadcast PHASE-SPLIT: 48 back-to-back v_readlane into SGPRs,
// sched_barrier, then 48 fmacs — avoids the VALU->SGPR->VALU forwarding
// hazard that a 1:1 readlane/fmac interleave pays (~4 cyc x 48 per step).
// Renorm via exact exponent extraction once per 8-step group; integer log2
// bookkeeping. Emissions double-buffered in LDS via global_load_lds.
// Code-size discipline: only the 8-step group body unrolled (I-cache resident).

constexpr int SEQ = 512, BN = 1024, TT = 48;
constexpr int CH = 64, NCH = SEQ / CH;
#define LOG2E 1.44269504088896340736f
#define LN2   0.69314718055994530942f

__device__ __forceinline__ float fexp2(float x) { return __builtin_amdgcn_exp2f(x); }
__device__ __forceinline__ float flog2(float x) { return __builtin_amdgcn_logf(x); }
__device__ __forceinline__ float rlane(float v, int i) {
    return __int_as_float(__builtin_amdgcn_readlane(__float_as_int(v), i));
}

__global__ __launch_bounds__(64, 1) void crf_fwd(
    const float* __restrict__ emis, const int* __restrict__ tags,
    const int* __restrict__ mask, const float* __restrict__ start_t,
    const float* __restrict__ end_t, const float* __restrict__ trans,
    float* __restrict__ ws)
{
    __shared__ float ltr[TT * TT];
    __shared__ __align__(16) float ebuf[2][CH * TT];  // 2 x 12 KB

    const int lane = threadIdx.x;
    const int b = blockIdx.x;

    const bool jv = (lane < TT);
    const int jc = jv ? lane : (TT - 1);

    // per-lane byte offsets for the 12 staging instrs (16B/lane each)
    int offs[12];
#pragma unroll
    for (int k = 0; k < 12; ++k) {
        const int g = k * 64 + lane;
        const int r = g / 12, j4 = g % 12;
        offs[k] = r * (BN * TT * 4) + j4 * 16;
    }

#define STAGE_CHUNK(tb, buf)                                                   \
    {                                                                          \
        const char* cb = (const char*)emis + ((size_t)(tb) * BN + b) * (TT * 4); \
        _Pragma("unroll")                                                      \
        for (int k = 0; k < 12; ++k) {                                         \
            __builtin_amdgcn_global_load_lds(                                  \
                (const __attribute__((address_space(1))) void*)(cb + offs[k]), \
                (__attribute__((address_space(3))) void*)(&ebuf[buf][k * 256]),\
                16, 0, 0);                                                     \
        }                                                                      \
    }

    // ---- prologue ----
    STAGE_CHUNK(0, 0);
    int tgv = tags[(size_t)lane * BN + b];
    int mkv = mask[(size_t)lane * BN + b];
    const int tag0 = tags[b];

    for (int i = lane; i < TT * TT; i += 64) ltr[i] = trans[i];
    __syncthreads();

    // lane j holds column j of E = exp(transitions); pin into VGPRs
    float E[TT];
#pragma unroll
    for (int i = 0; i < TT; ++i)
        E[i] = fexp2(ltr[i * TT + jc] * LOG2E);
#pragma unroll
    for (int i = 0; i < TT; ++i)
        asm volatile("" : "+v"(E[i]));

    const float st = start_t[jc];
    const float en = end_t[jc];

    asm volatile("s_waitcnt vmcnt(0)" ::: "memory");
    __builtin_amdgcn_sched_barrier(0);

    // init (t=0): r = exp(st + e0) * 2^-6
    const float e00 = ebuf[0][jc];
    float r = jv ? fexp2(fmaf(st + e00, LOG2E, -6.0f)) : 0.0f;
    int la = 6;  // uniform log2 bookkeeping

    float numpart = (lane == tag0) ? (st + e00) : 0.f;
    float numtr = 0.f, numem = 0.f;
    int mcount = 0;
    int carry_tag = tag0;

    STAGE_CHUNK(CH, 1);
    int tgn = tags[((size_t)CH + lane) * BN + b];
    int mkn = mask[((size_t)CH + lane) * BN + b];

    int cur = 0;

#pragma unroll 1
    for (int c = 0; c < NCH; ++c) {
        const int tbase = c * CH;
        const float* ebc = ebuf[cur];

        // ---- chunk-parallel numerator + mask word (off the serial chain) ----
        const int tmv = (mkv && (tbase + lane) > 0) ? tgv : -1;
        const unsigned long long vmword = __ballot(tmv >= 0);
        int tprev = __shfl_up(tgv, 1, 64);
        if (lane == 0) tprev = carry_tag;
        if (tmv >= 0) {
            numtr += ltr[tprev * TT + tgv];
            numem += ebc[lane * TT + tgv];
        }
        carry_tag = __builtin_amdgcn_readlane(tgv, 63);
        mcount += __popcll(__ballot(mkv != 0));
        la += 6 * (int)__popcll(vmword);

        // group-0 emission rows for this chunk
        float ev[8];
#pragma unroll
        for (int u = 0; u < 8; ++u) ev[u] = ebc[u * TT + jc];

        // ---- 8 groups x 8 serial steps (group loop NOT unrolled) ----
#pragma unroll 1
        for (int sc = 0; sc < 8; ++sc) {
            // emission multipliers for this group (off the serial chain)
            float emul[8];
#pragma unroll
            for (int u = 0; u < 8; ++u)
                emul[u] = fexp2(fmaf(ev[u], LOG2E, -6.0f));
            // issue next group's emission loads (WAR on ev, emul extracted)
            if (sc < 7) {
#pragma unroll
                for (int u = 0; u < 8; ++u)
                    ev[u] = ebc[((sc + 1) * 8 + u) * TT + jc];
            }
            // per-group commit bits (uniform)
            const unsigned gm = (unsigned)(vmword >> (sc * 8)) & 0xFFu;
            // renorm: exact power-of-2 scale from lane 0's exponent
            {
                const float r0 = rlane(r, 0);
                const int m = ((__float_as_int(r0) >> 23) & 0xFF) - 127;
                const float scl = __int_as_float((127 - m) << 23);
                r *= scl;
                la += m;
            }
            // 8 serial steps: phase-split broadcast matvec, gated commit
#pragma unroll
            for (int u = 0; u < 8; ++u) {
                // phase 1: 48 back-to-back readlanes (uniform -> SGPRs)
                float pp[TT];
#pragma unroll
                for (int i = 0; i < TT; ++i)
                    pp[i] = rlane(r, i);
                __builtin_amdgcn_sched_barrier(0);
                // phase 2: 48 fmacs, every SGPR operand long since written
                float q0 = 0.f, q1 = 0.f, q2 = 0.f, q3 = 0.f;
#pragma unroll
                for (int i = 0; i < TT; i += 4) {
                    q0 = fmaf(pp[i],     E[i],     q0);
                    q1 = fmaf(pp[i + 1], E[i + 1], q1);
                    q2 = fmaf(pp[i + 2], E[i + 2], q2);
                    q3 = fmaf(pp[i + 3], E[i + 3], q3);
                }
                const float q = (q0 + q1) + (q2 + q3);
                const bool commit = (gm >> u) & 1u;
                r = commit ? (q * emul[u]) : r;
            }
        }

        // ---- chunk boundary: drain staged loads, swap buffers ----
        asm volatile("s_waitcnt vmcnt(0)" ::: "memory");
        __builtin_amdgcn_sched_barrier(0);
        cur ^= 1;
        tgv = tgn; mkv = mkn;
        if (c + 2 < NCH) {
            STAGE_CHUNK(tbase + 2 * CH, cur ^ 1);
            tgn = tags[((size_t)(tbase + 2 * CH) + lane) * BN + b];
            mkn = mask[((size_t)(tbase + 2 * CH) + lane) * BN + b];
        }
    }

    // numerator: end transition at tags[sum(mask)-1]
    const int last_tag = tags[(size_t)(mcount - 1) * BN + b];  // uniform
    numpart += (lane == last_tag) ? en : 0.f;
    numpart += numtr + numem;

    // denominator: ln( sum_j r_j * exp(end_j) ) + la*ln2
    float v = jv ? (r * fexp2(en * LOG2E)) : 0.0f;
    float se = v;
#pragma unroll
    for (int d = 1; d < 64; d <<= 1)
        se += __shfl_xor(se, d, 64);
    const float den = (flog2(se) + (float)la) * LN2;

    float num = numpart;
#pragma unroll
    for (int d = 1; d < 64; d <<= 1)
        num += __shfl_xor(num, d, 64);

    if (lane == 0) ws[b] = num - den;
#undef STAGE_CHUNK
}

__global__ __launch_bounds__(256) void reduce_mean(
    const float* __restrict__ ws, float* __restrict__ out)
{
    const int tid = threadIdx.x;
    float v = ws[tid] + ws[tid + 256] + ws[tid + 512] + ws[tid + 768];
#pragma unroll
    for (int d = 1; d < 64; d <<= 1)
        v += __shfl_xor(v, d, 64);
    __shared__ float acc[4];
    if ((tid & 63) == 0) acc[tid >> 6] = v;
    __syncthreads();
    if (tid == 0) out[0] = (acc[0] + acc[1] + acc[2] + acc[3]) * (1.f / 1024.f);
}

extern "C" void kernel_launch(void* const* d_in, const int* in_sizes, int n_in,
                              void* d_out, int out_size, void* d_ws, size_t ws_size,
                              hipStream_t stream)
{
    const float* emis    = (const float*)d_in[0];
    const int*   tags    = (const int*)d_in[1];
    const int*   mask    = (const int*)d_in[2];
    const float* start_t = (const float*)d_in[3];
    const float* end_t   = (const float*)d_in[4];
    const float* trans   = (const float*)d_in[5];
    float* ws  = (float*)d_ws;
    float* out = (float*)d_out;

    crf_fwd<<<dim3(BN), dim3(64), 0, stream>>>(emis, tags, mask, start_t, end_t, trans, ws);
    reduce_mean<<<dim3(1), dim3(256), 0, stream>>>(ws, out);
}